// Round 1
// baseline (169.730 us; speedup 1.0000x reference)
//
#include <hip/hip_runtime.h>
#include <hip/hip_bf16.h>

#define BATCH 8
#define SEQ   2048
#define DIM   64

typedef __attribute__((ext_vector_type(8))) short short8;
typedef __attribute__((ext_vector_type(4))) float floatx4;

static __device__ __forceinline__ unsigned short f2bf(float x) {
    union { float f; unsigned u; } v; v.f = x;
    unsigned r = (v.u + 0x7FFFu + ((v.u >> 16) & 1u)) >> 16;
    return (unsigned short)r;
}

// ---- prep A: bf16 casts of Q,K rows + squared row norms -------------------
__global__ __launch_bounds__(256) void prep_rows(
        const float* __restrict__ Q, const float* __restrict__ K,
        unsigned short* __restrict__ Qb, unsigned short* __restrict__ Kb,
        float* __restrict__ q2, float* __restrict__ k2) {
    int wid  = (blockIdx.x * 256 + threadIdx.x) >> 6;   // one wave per row
    int lane = threadIdx.x & 63;
    const float* src; unsigned short* db; float* dn; int row;
    if (wid < BATCH * SEQ) { src = Q; db = Qb; dn = q2; row = wid; }
    else                   { src = K; db = Kb; dn = k2; row = wid - BATCH * SEQ; }
    float v = src[(size_t)row * DIM + lane];
    db[(size_t)row * DIM + lane] = f2bf(v);
    float s = v * v;
    #pragma unroll
    for (int off = 32; off; off >>= 1) s += __shfl_xor(s, off);
    if (lane == 0) dn[row] = s;
}

// ---- prep B: V -> Vt[b][d][t] bf16 (transposed) + column sums -------------
__global__ __launch_bounds__(256) void prep_vt(
        const float* __restrict__ V, unsigned short* __restrict__ Vt,
        float* __restrict__ csum) {
    __shared__ float tile[64][65];
    __shared__ float psum[4][64];
    int b  = blockIdx.x >> 5;
    int t0 = (blockIdx.x & 31) * 64;
    int i  = threadIdx.x;
    int d  = i & 63, g = i >> 6;
    float part = 0.f;
    #pragma unroll
    for (int p = 0; p < 16; ++p) {
        int tt = p * 4 + g;
        float v = V[((size_t)(b * SEQ + t0 + tt)) * DIM + d];
        tile[tt][d] = v;
        part += v;
    }
    psum[g][d] = part;
    __syncthreads();
    int tt = i & 63;
    #pragma unroll
    for (int p = 0; p < 16; ++p) {
        int dd = p * 4 + g;
        Vt[((size_t)(b * DIM + dd)) * SEQ + t0 + tt] = f2bf(tile[tt][dd]);
    }
    if (i < 64) {
        float s = psum[0][i] + psum[1][i] + psum[2][i] + psum[3][i];
        atomicAdd(&csum[b * DIM + i], s);
    }
}

// ---- main: flash-style shifted-softmax gaussian attention -----------------
// block = 4 waves; wave w owns 16 q-rows; 64-wide K/V tiles staged in LDS.
// P' = exp(w)-1 in bf16 keeps the softmax signal (p ~ 1+1e-5 would flush).
__global__ __launch_bounds__(256) void gauss_attn(
        const unsigned short* __restrict__ Qb, const unsigned short* __restrict__ Kb,
        const unsigned short* __restrict__ Vt, const float* __restrict__ q2,
        const float* __restrict__ k2, const float* __restrict__ csum,
        float* __restrict__ out) {
    // stride 72 (=64+8): 16B-aligned rows, 2-way bank aliasing on b128 reads (free)
    __shared__ __align__(16) unsigned short Klds[64 * 72];
    __shared__ __align__(16) unsigned short Vlds[64 * 72];
    __shared__ __align__(16) unsigned short Plds[4][16 * 72];
    __shared__ float k2lds[64];

    const int b    = blockIdx.x >> 5;
    const int q0   = (blockIdx.x & 31) * 64;
    const int tid  = threadIdx.x;
    const int w    = tid >> 6;
    const int lane = tid & 63;
    const int l15  = lane & 15;
    const int quad = lane >> 4;
    const int qrow0 = q0 + w * 16;

    // Q fragments (A operand): A[m=lane&15][k=quad*8+j], kc = k-chunk of 32
    short8 qf[2];
    #pragma unroll
    for (int kc = 0; kc < 2; ++kc)
        qf[kc] = *(const short8*)(Qb + ((size_t)(b * SEQ + qrow0 + l15)) * DIM + kc * 32 + quad * 8);
    // q2 for this lane's C-layout rows (quad*4 + r)
    floatx4 q2v = *(const floatx4*)(q2 + b * SEQ + qrow0 + quad * 4);

    floatx4 acc[4]; floatx4 den;
    #pragma unroll
    for (int nt = 0; nt < 4; ++nt) acc[nt] = (floatx4){0.f, 0.f, 0.f, 0.f};
    den = (floatx4){0.f, 0.f, 0.f, 0.f};

    // ones B-fragment: column n=0 all ones -> row sums of P' land in col 0
    short8 ones;
    {
        short o = (l15 == 0) ? (short)0x3F80 : (short)0;
        #pragma unroll
        for (int j = 0; j < 8; ++j) ones[j] = o;
    }

    unsigned short* Pw = Plds[w];

    for (int t0 = 0; t0 < SEQ; t0 += 64) {
        // ---- stage K tile (row-major) and Vt tile (d-major) ----
        {
            int tt = tid >> 3, dg = tid & 7;
            *(uint4*)&Klds[tt * 72 + dg * 8] =
                *(const uint4*)(Kb + ((size_t)(b * SEQ + t0 + tt)) * DIM + dg * 8);
            *(uint4*)&Klds[(tt + 32) * 72 + dg * 8] =
                *(const uint4*)(Kb + ((size_t)(b * SEQ + t0 + tt + 32)) * DIM + dg * 8);
            *(uint4*)&Vlds[tt * 72 + dg * 8] =
                *(const uint4*)(Vt + ((size_t)(b * DIM + tt)) * SEQ + t0 + dg * 8);
            *(uint4*)&Vlds[(tt + 32) * 72 + dg * 8] =
                *(const uint4*)(Vt + ((size_t)(b * DIM + tt + 32)) * SEQ + t0 + dg * 8);
            if (tid < 64) k2lds[tid] = k2[b * SEQ + t0 + tid];
        }
        __syncthreads();

        // ---- QK^T (B^T pattern) + scoring, write P' bf16 to LDS ----
        #pragma unroll
        for (int nt = 0; nt < 4; ++nt) {
            short8 kf0 = *(const short8*)&Klds[(nt * 16 + l15) * 72 + 0 * 32 + quad * 8];
            short8 kf1 = *(const short8*)&Klds[(nt * 16 + l15) * 72 + 1 * 32 + quad * 8];
            floatx4 sc = (floatx4){0.f, 0.f, 0.f, 0.f};
            sc = __builtin_amdgcn_mfma_f32_16x16x32_bf16(qf[0], kf0, sc, 0, 0, 0);
            sc = __builtin_amdgcn_mfma_f32_16x16x32_bf16(qf[1], kf1, sc, 0, 0, 0);
            float k2n = k2lds[nt * 16 + l15];
            #pragma unroll
            for (int r = 0; r < 4; ++r) {
                float d2   = fmaxf(fmaf(-2.f, sc[r], q2v[r] + k2n), 0.f);
                float dist = sqrtf(d2);
                float wgt  = __expf(-dist);
                // p' = expm1(wgt): series for tiny wgt (the common case), exp-1 else
                float e1 = __expf(wgt) - 1.f;
                float pl = wgt * fmaf(wgt, fmaf(wgt, 0.16666667f, 0.5f), 1.f);
                float pv = (wgt > 0.03f) ? e1 : pl;
                Pw[(quad * 4 + r) * 72 + nt * 16 + l15] = f2bf(pv);
            }
        }

        // ---- P'V + row-sum(P') via ones column ----
        #pragma unroll
        for (int tc = 0; tc < 2; ++tc) {
            short8 pf = *(const short8*)&Pw[l15 * 72 + tc * 32 + quad * 8];
            #pragma unroll
            for (int nt = 0; nt < 4; ++nt) {
                short8 vf = *(const short8*)&Vlds[(nt * 16 + l15) * 72 + tc * 32 + quad * 8];
                acc[nt] = __builtin_amdgcn_mfma_f32_16x16x32_bf16(pf, vf, acc[nt], 0, 0, 0);
            }
            den = __builtin_amdgcn_mfma_f32_16x16x32_bf16(pf, ones, den, 0, 0, 0);
        }
        __syncthreads();
    }

    // ---- epilogue: out = (csumV + P'V) / (S + rowsum P') ----
    float rcp[4];
    #pragma unroll
    for (int r = 0; r < 4; ++r) {
        float rs = __shfl(den[r], lane & 48);   // broadcast col-0 lane of this quad
        rcp[r] = 1.f / (2048.f + rs);
    }
    #pragma unroll
    for (int nt = 0; nt < 4; ++nt) {
        float cs = csum[b * DIM + nt * 16 + l15];
        #pragma unroll
        for (int r = 0; r < 4; ++r) {
            out[((size_t)(b * SEQ + qrow0 + quad * 4 + r)) * DIM + nt * 16 + l15] =
                (cs + acc[nt][r]) * rcp[r];
        }
    }
}

extern "C" void kernel_launch(void* const* d_in, const int* in_sizes, int n_in,
                              void* d_out, int out_size, void* d_ws, size_t ws_size,
                              hipStream_t stream) {
    const float* Q = (const float*)d_in[0];
    const float* K = (const float*)d_in[1];
    const float* V = (const float*)d_in[2];
    float* out = (float*)d_out;

    char* ws = (char*)d_ws;
    unsigned short* Qb = (unsigned short*)(ws);                        // 2 MB
    unsigned short* Kb = (unsigned short*)(ws + (2u << 20));           // 2 MB
    unsigned short* Vt = (unsigned short*)(ws + (4u << 20));           // 2 MB
    float* q2   = (float*)(ws + (6u << 20));                           // 64 KB
    float* k2   = (float*)(ws + (6u << 20) + (64u << 10));             // 64 KB
    float* csum = (float*)(ws + (6u << 20) + (128u << 10));            // 2 KB

    hipMemsetAsync(csum, 0, BATCH * DIM * sizeof(float), stream);
    prep_rows<<<(2 * BATCH * SEQ) / 4, 256, 0, stream>>>(Q, K, Qb, Kb, q2, k2);
    prep_vt<<<BATCH * (SEQ / 64), 256, 0, stream>>>(V, Vt, csum);
    gauss_attn<<<BATCH * (SEQ / 64), 256, 0, stream>>>(Qb, Kb, Vt, q2, k2, csum, out);
}